// Round 2
// baseline (4653.996 us; speedup 1.0000x reference)
//
#include <hip/hip_runtime.h>
#include <hip/hip_bf16.h>
#include <math.h>

// Archetipes RNN scan: T=256 sequential steps, M=16 modules, H=256, I=128.
// ALL float I/O is float32 (R1 post-mortem: no bf16 eps floor in harness
// threshold => _any_bf16=False; bf16 misread caused NaN).
//
// Persistent-kernel design: 256 blocks x 1024 threads (1 block/CU, all
// co-resident), monotone grid barrier (graph-replay safe, validated R1 —
// kernel completed without deadlock), hy ping-pong in d_ws exchanged via
// agent-scope atomics (bypass non-coherent per-XCD L2; no bulk fences so
// wm stays L2-resident).
//
// Work layout: block b <-> h=b, wave w <-> module m=w. Every block does
// exactly sum_m(ocnt_m)*H + H + I MACs per wave -> perfect CU load balance.

#define DT_C    0.042f
#define GAMMA_C 2.7f
#define EPS_C   4.7f

constexpr int M = 16, H = 256, I = 128, T = 256;
constexpr int NROW = M * H;   // 4096
constexpr int NBLK = H;       // 256 blocks
constexpr int NTHR = 1024;    // 16 waves

// Monotone barrier slots: never reset; each launch adds exactly 256 arrivals
// per slot, target = (v & ~255) + 256. Survives graph replays indefinitely.
__device__ unsigned int g_bar[256];

__device__ __forceinline__ void grid_barrier(int slot) {
  __syncthreads();   // drains vmcnt -> all this block's stores are through
  if (threadIdx.x == 0) {
    unsigned int v = __hip_atomic_fetch_add(&g_bar[slot], 1u, __ATOMIC_ACQ_REL,
                                            __HIP_MEMORY_SCOPE_AGENT);
    unsigned int target = (v & ~255u) + 256u;
    while (__hip_atomic_load(&g_bar[slot], __ATOMIC_ACQUIRE,
                             __HIP_MEMORY_SCOPE_AGENT) < target) {
      __builtin_amdgcn_s_sleep(1);
    }
  }
  __syncthreads();
}

__global__ __launch_bounds__(NTHR, 1) void rnn_persistent(
    const float* __restrict__ x,      // T*I
    const float* __restrict__ wm,     // M*M*H*H
    const float* __restrict__ conn,   // M*M
    const float* __restrict__ mask,   // M
    const float* __restrict__ W_in,   // M*H*I
    const float* __restrict__ W_rec,  // M*H*H
    const float* __restrict__ bias,   // M*H
    float* __restrict__ out,          // T*M*2*H state_seq, then T*M*H fb_seq
    float* hy_ws)                     // 2*NROW ping-pong
{
  const int b    = blockIdx.x;    // h
  const int tid  = threadIdx.x;
  const int w    = tid >> 6;      // wave = module m
  const int lane = tid & 63;

  __shared__ float hy_lds[NROW];        // 16 KB
  __shared__ float s_c[M * M];
  __shared__ float s_scal[M];
  __shared__ int   s_olist[M][M];
  __shared__ float s_oc[M][M];
  __shared__ int   s_ocnt[M];

  if (tid < M * M) s_c[tid] = conn[tid];
  __syncthreads();
  if (tid < M) {
    float s = 0.f; int cnt = 0;
    for (int o = 0; o < M; ++o) {
      float c = s_c[tid * M + o];
      s += c;
      if (c != 0.f) { s_olist[tid][cnt] = o; s_oc[tid][cnt] = c; ++cnt; }
    }
    s_ocnt[tid] = cnt;
    s_scal[tid] = 1.0f / fmaxf(s, 1.0f);
  }
  __syncthreads();

  const int   m     = w;
  const int   h     = b;
  const int   row   = m * H + h;
  const float maskm = mask[m];
  const float biasv = bias[row];
  const float scal  = s_scal[m];
  const int   ocnt  = s_ocnt[m];

  // init hy buffer 0 (read at t=0) to zeros; hz lives in lane0 register
  if (lane == 0)
    __hip_atomic_store(&hy_ws[row], 0.0f, __ATOMIC_RELAXED, __HIP_MEMORY_SCOPE_AGENT);
  float hz = 0.f;

  grid_barrier(0);

  for (int t = 0; t < T; ++t) {
    // stage full hy_{t-1} into LDS (agent-scope loads bypass stale L1/L2)
    const float* hy_src = hy_ws + (size_t)(t & 1) * NROW;
    for (int i = tid; i < NROW; i += NTHR)
      hy_lds[i] = __hip_atomic_load(&hy_src[i], __ATOMIC_RELAXED, __HIP_MEMORY_SCOPE_AGENT);
    __syncthreads();

    float acc_fb = 0.f;   // feedback dot (scaled later)
    float acc_o  = 0.f;   // input + recurrent dots

    // input term: lane covers i = 2*lane .. 2*lane+1 of I=128
    {
      const float2 xd = *reinterpret_cast<const float2*>(x + (size_t)t * I + 2 * lane);
      const float2 wd = *reinterpret_cast<const float2*>(W_in + (size_t)row * I + 2 * lane);
      acc_o = fmaf(wd.x, maskm * xd.x, acc_o);
      acc_o = fmaf(wd.y, maskm * xd.y, acc_o);
    }
    // recurrent term: lane covers g = 4*lane .. 4*lane+3 of H=256
    {
      const float4 wd = *reinterpret_cast<const float4*>(W_rec + (size_t)row * H + 4 * lane);
      const float* hp = &hy_lds[m * H + 4 * lane];
      acc_o = fmaf(wd.x, hp[0], acc_o);
      acc_o = fmaf(wd.y, hp[1], acc_o);
      acc_o = fmaf(wd.z, hp[2], acc_o);
      acc_o = fmaf(wd.w, hp[3], acc_o);
    }
    // feedback: only active o blocks (conn != 0)
    for (int k = 0; k < ocnt; ++k) {
      const int   o = s_olist[m][k];
      const float c = s_oc[m][k];
      const float4 wd = *reinterpret_cast<const float4*>(
          wm + ((size_t)(m * M + o) * H + h) * H + 4 * lane);
      const float* hp = &hy_lds[o * H + 4 * lane];
      float po = wd.x * hp[0];
      po = fmaf(wd.y, hp[1], po);
      po = fmaf(wd.z, hp[2], po);
      po = fmaf(wd.w, hp[3], po);
      acc_fb = fmaf(c, po, acc_fb);
    }

    // wave-wide butterfly reduce (64 lanes)
    for (int off = 32; off > 0; off >>= 1) {
      acc_fb += __shfl_xor(acc_fb, off);
      acc_o  += __shfl_xor(acc_o,  off);
    }

    if (lane == 0) {
      const float fb   = scal * acc_fb;
      const float hy_p = hy_lds[row];
      const float pre  = acc_o + biasv + fb;
      const float hz_n = hz + DT_C * (tanhf(pre) - GAMMA_C * hy_p - EPS_C * hz);
      const float hy_n = hy_p + DT_C * hz_n;
      hz = hz_n;
      // publish hy_t into the other buffer (agent scope, bypasses XCD L2)
      __hip_atomic_store(&hy_ws[(size_t)((t + 1) & 1) * NROW + row], hy_n,
                         __ATOMIC_RELAXED, __HIP_MEMORY_SCOPE_AGENT);
      // outputs: state_seq[t][m][0][h], state_seq[t][m][1][h], fb_seq[t][m][h]
      const size_t so = (size_t)t * (M * 2 * H) + (size_t)m * (2 * H);
      out[so + h]     = hy_n;
      out[so + H + h] = hz_n;
      out[(size_t)T * M * 2 * H + (size_t)t * (M * H) + row] = fb;
    }

    if (t != T - 1) grid_barrier(t + 1);
  }
}

extern "C" void kernel_launch(void* const* d_in, const int* in_sizes, int n_in,
                              void* d_out, int out_size, void* d_ws, size_t ws_size,
                              hipStream_t stream) {
  const float* x     = (const float*)d_in[0];
  const float* wm    = (const float*)d_in[1];
  const float* conn  = (const float*)d_in[2];
  const float* mask  = (const float*)d_in[3];
  const float* W_in  = (const float*)d_in[4];
  const float* W_rec = (const float*)d_in[5];
  const float* bias  = (const float*)d_in[6];

  rnn_persistent<<<NBLK, NTHR, 0, stream>>>(
      x, wm, conn, mask, W_in, W_rec, bias,
      (float*)d_out, (float*)d_ws);
}

// Round 3
// 3506.904 us; speedup vs baseline: 1.3271x; 1.3271x over previous
//
#include <hip/hip_runtime.h>
#include <math.h>

// Archetipes RNN scan: T=256 sequential steps, M=16 modules, H=256, I=128.
// R3: register-resident weights. R2 counters showed 10.1 MB/step of L2-miss
// traffic (FETCH 2.53 GB @ 588 GB/s effective) because the per-XCD wm
// working set (32 blocks x ~131 KB = 4.2 MB) just overflows the 4 MB L2.
// Weights are step-invariant: hold them in VGPRs (<=16 x float4 per lane
// = <=64 VGPRs, fits the 128/wave budget at 4 waves/SIMD) -> per-step
// weight traffic is ZERO. Only the 16 KB/block hy all-to-all remains.
//
// Persistent kernel: 256 blocks x 1024 threads (1 block/CU), monotone grid
// barrier (graph-replay safe, validated R2), hy ping-pong in d_ws via
// agent-scope atomics (bypasses non-coherent per-XCD L1/L2 - ping-pong
// parity reuses addresses every 2 steps, so coherent access is required).
// Work layout: block b <-> h=b, wave w <-> module m=w (perfect balance).

#define DT_C    0.042f
#define GAMMA_C 2.7f
#define EPS_C   4.7f

constexpr int M = 16, H = 256, I = 128, T = 256;
constexpr int NROW = M * H;   // 4096
constexpr int NBLK = 256;
constexpr int NTHR = 1024;    // 16 waves

typedef float f32x4 __attribute__((ext_vector_type(4)));
typedef unsigned long long u64;

// Monotone barrier: never reset; each launch adds exactly 256 arrivals per
// slot, target = (v & ~255) + 256. Survives graph replays indefinitely.
__device__ unsigned int g_bar[256];

__device__ __forceinline__ void grid_barrier(int slot) {
  __syncthreads();   // drains vmcnt -> this block's hy store is through
  if (threadIdx.x == 0) {
    unsigned int v = __hip_atomic_fetch_add(&g_bar[slot], 1u, __ATOMIC_ACQ_REL,
                                            __HIP_MEMORY_SCOPE_AGENT);
    unsigned int target = (v & ~255u) + 256u;
    while (__hip_atomic_load(&g_bar[slot], __ATOMIC_ACQUIRE,
                             __HIP_MEMORY_SCOPE_AGENT) < target) {
      __builtin_amdgcn_s_sleep(1);
    }
  }
  __syncthreads();
}

__global__ __launch_bounds__(NTHR) void rnn_persistent(
    const float* __restrict__ x,      // T*I
    const float* __restrict__ wm,     // M*M*H*H
    const float* __restrict__ conn,   // M*M
    const float* __restrict__ mask,   // M
    const float* __restrict__ W_in,   // M*H*I
    const float* __restrict__ W_rec,  // M*H*H
    const float* __restrict__ bias,   // M*H
    float* __restrict__ out,          // T*M*2*H state_seq, then T*M*H fb_seq
    float* hy_ws)                     // 2*NROW ping-pong
{
  const int h    = blockIdx.x;
  const int tid  = threadIdx.x;
  const int m    = tid >> 6;      // wave = module
  const int lane = tid & 63;

  __shared__ float hy_lds[NROW];        // 16 KB
  __shared__ float s_c[M * M];
  __shared__ float s_scal[M];
  __shared__ int   s_olist[M][M];
  __shared__ float s_oc[M][M];
  __shared__ int   s_ocnt[M];

  if (tid < M * M) s_c[tid] = conn[tid];
  __syncthreads();
  if (tid < M) {
    float s = 0.f; int cnt = 0;
    for (int o = 0; o < M; ++o) {
      float c = s_c[tid * M + o];
      s += c;
      if (c != 0.f) { s_olist[tid][cnt] = o; s_oc[tid][cnt] = c; ++cnt; }
    }
    for (int k = cnt; k < M; ++k) { s_olist[tid][k] = 0; s_oc[tid][k] = 0.f; }
    s_ocnt[tid] = cnt;
    s_scal[tid] = 1.0f / fmaxf(s, 1.0f);
  }
  __syncthreads();

  const int   row   = m * H + h;
  const float maskm = mask[m];
  const float biasv = bias[row];
  const float scal  = s_scal[m];
  const int   ocnt  = s_ocnt[m];

  // ---- one-time: weights into registers (fp32, full precision) ----
  // wreg[k] holds wm[(m,o_k), h, 4*lane..4*lane+3] * conn[m,o_k].
  // Unrolled with wave-uniform guards: no dynamic register indexing.
  f32x4 wreg[M];
#pragma unroll
  for (int k = 0; k < M; ++k) {
    if (k < ocnt) {
      const int o = s_olist[m][k];
      const f32x4 wv = *reinterpret_cast<const f32x4*>(
          wm + ((size_t)(m * M + o) * H + h) * H + 4 * lane);
      wreg[k] = wv * s_oc[m][k];
    } else {
      wreg[k] = (f32x4)0.f;
    }
  }
  const f32x4  wrec = *reinterpret_cast<const f32x4*>(W_rec + (size_t)row * H + 4 * lane);
  const float2 win  = *reinterpret_cast<const float2*>(W_in + (size_t)row * I + 2 * lane);

  // init hy buffer 0 (read at t=0); hz lives in lane0 register
  if (lane == 0)
    __hip_atomic_store(&hy_ws[row], 0.0f, __ATOMIC_RELAXED, __HIP_MEMORY_SCOPE_AGENT);
  float hz = 0.f;

  grid_barrier(0);

  for (int t = 0; t < T; ++t) {
    // stage hy_{t-1}: 2x 8-byte agent-scope loads per thread (coherent,
    // vectorized to global_load_dwordx2 with sc bits), then LDS
    {
      const u64* src = reinterpret_cast<const u64*>(hy_ws + (size_t)(t & 1) * NROW) + 2 * tid;
      u64 a = __hip_atomic_load(src,     __ATOMIC_RELAXED, __HIP_MEMORY_SCOPE_AGENT);
      u64 b = __hip_atomic_load(src + 1, __ATOMIC_RELAXED, __HIP_MEMORY_SCOPE_AGENT);
      u64* dst = reinterpret_cast<u64*>(&hy_lds[4 * tid]);
      dst[0] = a; dst[1] = b;
    }
    __syncthreads();

    // input term
    const float2 xd = *reinterpret_cast<const float2*>(x + (size_t)t * I + 2 * lane);
    float acc_o = win.x * (maskm * xd.x);
    acc_o = fmaf(win.y, maskm * xd.y, acc_o);
    // recurrent term
    {
      const f32x4 hp = *reinterpret_cast<const f32x4*>(&hy_lds[m * H + 4 * lane]);
      acc_o = fmaf(wrec.x, hp.x, acc_o);
      acc_o = fmaf(wrec.y, hp.y, acc_o);
      acc_o = fmaf(wrec.z, hp.z, acc_o);
      acc_o = fmaf(wrec.w, hp.w, acc_o);
    }
    // feedback: register weights x LDS hy fragments
    float acc_fb = 0.f;
#pragma unroll
    for (int k = 0; k < M; ++k) {
      if (k < ocnt) {
        const int o = s_olist[m][k];
        const f32x4 hp = *reinterpret_cast<const f32x4*>(&hy_lds[o * H + 4 * lane]);
        float po = wreg[k].x * hp.x;
        po = fmaf(wreg[k].y, hp.y, po);
        po = fmaf(wreg[k].z, hp.z, po);
        po = fmaf(wreg[k].w, hp.w, po);
        acc_fb += po;
      }
    }

    // wave-wide butterfly reduce
    for (int off = 32; off > 0; off >>= 1) {
      acc_fb += __shfl_xor(acc_fb, off);
      acc_o  += __shfl_xor(acc_o,  off);
    }

    if (lane == 0) {
      const float fb   = scal * acc_fb;
      const float hy_p = hy_lds[row];
      const float pre  = acc_o + biasv + fb;
      const float hz_n = hz + DT_C * (tanhf(pre) - GAMMA_C * hy_p - EPS_C * hz);
      const float hy_n = hy_p + DT_C * hz_n;
      hz = hz_n;
      __hip_atomic_store(&hy_ws[(size_t)((t + 1) & 1) * NROW + row], hy_n,
                         __ATOMIC_RELAXED, __HIP_MEMORY_SCOPE_AGENT);
      const size_t so = (size_t)t * (M * 2 * H) + (size_t)m * (2 * H);
      out[so + h]     = hy_n;
      out[so + H + h] = hz_n;
      out[(size_t)T * M * 2 * H + (size_t)t * (M * H) + row] = fb;
    }

    if (t != T - 1) grid_barrier(t + 1);
  }
}

extern "C" void kernel_launch(void* const* d_in, const int* in_sizes, int n_in,
                              void* d_out, int out_size, void* d_ws, size_t ws_size,
                              hipStream_t stream) {
  const float* x     = (const float*)d_in[0];
  const float* wm    = (const float*)d_in[1];
  const float* conn  = (const float*)d_in[2];
  const float* mask  = (const float*)d_in[3];
  const float* W_in  = (const float*)d_in[4];
  const float* W_rec = (const float*)d_in[5];
  const float* bias  = (const float*)d_in[6];

  rnn_persistent<<<NBLK, NTHR, 0, stream>>>(
      x, wm, conn, mask, W_in, W_rec, bias,
      (float*)d_out, (float*)d_ws);
}